// Round 7
// baseline (1140.891 us; speedup 1.0000x reference)
//
#include <hip/hip_runtime.h>

// NeuralConvNetwork (Duvenaud fingerprint GNN), MI355X.
// Round 7: split-kernel restructure. R6 proved the fused kernel's gather is
// MLP-capped (~31 lines in flight/CU -> ~925 GB/s) because gather/GEMM are
// barrier-phased and blocks/CU stayed 2; vmcnt in-order drain forbids
// intra-wave pipelining past the GEMM's weight loads. New structure:
//   - gather_nbr kernel: pure scattered-load -> sum -> sequential store of
//     Hg[500k x 100] bf16 (nbr sums). No AGPR/LDS -> 8 waves/SIMD, loads in
//     flight continuously.
//   - bond sums are layer-invariant: bond_prep computes bsum[500k x 8] ONCE.
//   - layer_gemm: stages H = [self | nbr(Hg) | bond(bsum)] with sequential
//     loads, then the proven MFMA GEMM + norm/relu (+ fused molsum) epilogue.
//   - needs ~309 MB workspace; falls back to the proven R6 fused path if
//     ws_size is insufficient.

#define XS 100   // bf16 elems per intermediate activation row (exact)

typedef __attribute__((ext_vector_type(8))) short short8;
typedef __attribute__((ext_vector_type(4))) float float4v;

__device__ __forceinline__ float bf2f(unsigned u) { return __uint_as_float(u << 16); }
__device__ __forceinline__ unsigned short f2bf(float f) {
    unsigned b = __float_as_uint(f);
    return (unsigned short)((b + 0x7FFFu + ((b >> 16) & 1u)) >> 16);  // RNE
}
__device__ __forceinline__ unsigned pack2(float a, float b) {
    return (unsigned)f2bf(a) | ((unsigned)f2bf(b) << 16);
}
__device__ __forceinline__ void rowseg(int r, int& deg, int& seg) {
    if (r < 100000)      { deg = 1; seg = 0;      }
    else if (r < 275000) { deg = 2; seg = 100000; }
    else if (r < 425000) { deg = 3; seg = 275000; }
    else                 { deg = 4; seg = 425000; }
}

// ---- weight prep: Wt[dg][n][k]; k<F_IN -> Ws[k][n], SELF_PAD<=k<SELF_PAD+F_IN
//      -> Wd[dg][k-SELF_PAD][n], 2*SELF_PAD<=k<2*SELF_PAD+6 -> Wd bond rows.
__global__ void prep_weights(const float* __restrict__ Ws, const float* __restrict__ bs,
                             const float* __restrict__ Wd, const float* __restrict__ bd,
                             int F_IN, int F_OUT, int F_OUT_PAD, int KP, int SELF_PAD,
                             unsigned short* __restrict__ Wt, float* __restrict__ bc)
{
    int id = blockIdx.x * 256 + threadIdx.x;
    int total = 4 * F_OUT_PAD * KP;
    if (id >= total) return;
    int k  = id % KP;
    int nq = (id / KP) % F_OUT_PAD;
    int dg = id / (KP * F_OUT_PAD);
    float v = 0.f;
    if (nq < F_OUT) {
        if (k < F_IN)                                   v = Ws[(size_t)k * F_OUT + nq];
        else if (k >= SELF_PAD && k < SELF_PAD + F_IN)  v = Wd[((size_t)dg * (F_IN + 6) + (k - SELF_PAD)) * F_OUT + nq];
        else if (k >= 2 * SELF_PAD && k < 2 * SELF_PAD + 6)
            v = Wd[((size_t)dg * (F_IN + 6) + F_IN + (k - 2 * SELF_PAD)) * F_OUT + nq];
    }
    Wt[id] = f2bf(v);
    if (k == 0)
        bc[dg * F_OUT_PAD + nq] = (nq < F_OUT) ? (bs[nq] + bd[(size_t)dg * F_OUT + nq]) : 0.f;
}

// ---- bond sums (layer-invariant): bsum[r][0..5] = sum_d bondf[bn[r][d]][:], [6..7]=0
__global__ __launch_bounds__(256) void bond_prep(
    const float* __restrict__ bondf,
    const int* __restrict__ bn1, const int* __restrict__ bn2,
    const int* __restrict__ bn3, const int* __restrict__ bn4,
    unsigned short* __restrict__ bs)
{
    int r = blockIdx.x * 256 + threadIdx.x;
    if (r >= 500000) return;
    int deg, seg; rowseg(r, deg, seg);
    const int* bn = (deg == 1) ? bn1 : (deg == 2) ? bn2 : (deg == 3) ? bn3 : bn4;
    size_t ri = (size_t)(r - seg) * deg;
    int bi[4];
    #pragma unroll
    for (int d = 0; d < 4; ++d) if (d < deg) bi[d] = bn[ri + d];
    float2 v0[4], v1[4], v2[4];
    #pragma unroll
    for (int d = 0; d < 4; ++d)
        if (d < deg) {
            const float* bp = bondf + (size_t)bi[d] * 6;
            v0[d] = *(const float2*)bp;
            v1[d] = *(const float2*)(bp + 2);
            v2[d] = *(const float2*)(bp + 4);
        }
    float s0 = 0.f, s1 = 0.f, s2 = 0.f, s3 = 0.f, s4 = 0.f, s5 = 0.f;
    #pragma unroll
    for (int d = 0; d < 4; ++d)
        if (d < deg) {
            s0 += v0[d].x; s1 += v0[d].y; s2 += v1[d].x;
            s3 += v1[d].y; s4 += v2[d].x; s5 += v2[d].y;
        }
    uint4 w; w.x = pack2(s0, s1); w.y = pack2(s2, s3); w.z = pack2(s4, s5); w.w = 0;
    *(uint4*)(bs + (size_t)r * 8) = w;
}

// ---- standalone neighbor gather, bf16 x rows (XS=100) -> Hg[500k x 100] bf16.
// thread (row-pair rp, chunk c<25): 2 rows (rp, rp+250000), all loads batched.
__global__ __launch_bounds__(256) void gather_nbr_bf16(
    const unsigned short* __restrict__ x,
    const int* __restrict__ an1, const int* __restrict__ an2,
    const int* __restrict__ an3, const int* __restrict__ an4,
    unsigned short* __restrict__ Hg)
{
    int tid = blockIdx.x * 256 + threadIdx.x;
    int c  = tid & 31;
    int rp = tid >> 5;                 // 0..249999
    if (c >= 25) return;
    int rows[2] = { rp, rp + 250000 };
    int ai[2][4]; int dg[2];
    #pragma unroll
    for (int h = 0; h < 2; ++h) {
        int deg, seg; rowseg(rows[h], deg, seg); dg[h] = deg;
        const int* an = (deg == 1) ? an1 : (deg == 2) ? an2 : (deg == 3) ? an3 : an4;
        size_t ri = (size_t)(rows[h] - seg) * deg;
        #pragma unroll
        for (int d = 0; d < 4; ++d) if (d < deg) ai[h][d] = an[ri + d];
    }
    uint2 nv[2][4];
    #pragma unroll
    for (int h = 0; h < 2; ++h)
        #pragma unroll
        for (int d = 0; d < 4; ++d)
            if (d < dg[h]) nv[h][d] = *(const uint2*)(x + (size_t)ai[h][d] * XS + c * 4);
    #pragma unroll
    for (int h = 0; h < 2; ++h) {
        float s0 = 0.f, s1 = 0.f, s2 = 0.f, s3 = 0.f;
        #pragma unroll
        for (int d = 0; d < 4; ++d)
            if (d < dg[h]) {
                s0 += bf2f(nv[h][d].x & 0xFFFFu); s1 += bf2f(nv[h][d].x >> 16);
                s2 += bf2f(nv[h][d].y & 0xFFFFu); s3 += bf2f(nv[h][d].y >> 16);
            }
        uint2 o; o.x = pack2(s0, s1); o.y = pack2(s2, s3);
        *(uint2*)(Hg + (size_t)rows[h] * 100 + c * 4) = o;
    }
}

// ---- standalone neighbor gather, fp32 atomf rows (62) -> Hg[500k x 64] bf16.
__global__ __launch_bounds__(256) void gather_nbr_f32(
    const float* __restrict__ x,
    const int* __restrict__ an1, const int* __restrict__ an2,
    const int* __restrict__ an3, const int* __restrict__ an4,
    unsigned short* __restrict__ Hg)
{
    int tid = blockIdx.x * 256 + threadIdx.x;
    int c  = tid & 31;
    int rp = tid >> 5;
    if (c == 31) {                     // pad cols [62,64)
        *(unsigned*)(Hg + (size_t)rp * 64 + 62) = 0;
        *(unsigned*)(Hg + (size_t)(rp + 250000) * 64 + 62) = 0;
        return;
    }
    int rows[2] = { rp, rp + 250000 };
    int ai[2][4]; int dg[2];
    #pragma unroll
    for (int h = 0; h < 2; ++h) {
        int deg, seg; rowseg(rows[h], deg, seg); dg[h] = deg;
        const int* an = (deg == 1) ? an1 : (deg == 2) ? an2 : (deg == 3) ? an3 : an4;
        size_t ri = (size_t)(rows[h] - seg) * deg;
        #pragma unroll
        for (int d = 0; d < 4; ++d) if (d < deg) ai[h][d] = an[ri + d];
    }
    float2 nv[2][4];
    #pragma unroll
    for (int h = 0; h < 2; ++h)
        #pragma unroll
        for (int d = 0; d < 4; ++d)
            if (d < dg[h]) nv[h][d] = *(const float2*)(x + (size_t)ai[h][d] * 62 + c * 2);
    #pragma unroll
    for (int h = 0; h < 2; ++h) {
        float s0 = 0.f, s1 = 0.f;
        #pragma unroll
        for (int d = 0; d < 4; ++d)
            if (d < dg[h]) { s0 += nv[h][d].x; s1 += nv[h][d].y; }
        *(unsigned*)(Hg + (size_t)rows[h] * 64 + c * 2) = pack2(s0, s1);
    }
}

// ---- layer kernel: sequential stage of H + MFMA GEMM + epilogue (proven R6 math)
template<int F_IN, int F_OUT, int F_OUT_PAD, int SELF_PAD, bool LAST, bool FP32SELF>
__global__ __launch_bounds__(512, 4) void layer_gemm(
    const void* __restrict__ xin,           // fp32[500k,62] or bf16[500k,100]
    const unsigned short* __restrict__ Hg,  // bf16 [500k, 64 or 100]
    const unsigned short* __restrict__ bsv2,// bf16 [500k, 8] bond sums
    const unsigned short* __restrict__ Wt,  // [4][F_OUT_PAD][KP] bf16
    const float* __restrict__ bcomb,        // [4][F_OUT_PAD] fp32
    unsigned short* __restrict__ xout,      // layers 0/1: [500000, XS] bf16
    float* __restrict__ molout)             // layer 2:    [25000, 512] fp32
{
    constexpr int KP   = (2 * SELF_PAD + 6 + 31) & ~31;   // 160 / 224
    constexpr int SP   = KP + 8;
    constexpr int NT   = F_OUT_PAD / 16;                  // 7 / 32
    constexpr int JMAX = (NT + 7) / 8;                    // 1 / 4

    __shared__ __align__(16) unsigned short Hs[48 * SP];
    __shared__ float ssqs[8][48];

    const int R0 = blockIdx.x * 40;
    int deg, seg; rowseg(R0, deg, seg); (void)seg;
    const int tid = threadIdx.x;

    // ---- stage H (all writes disjoint; zeros cover never-written ranges)
    if constexpr (!FP32SELF) {
        if (tid < 40) {
            *(uint2*)&Hs[tid * SP + 100] = make_uint2(0, 0);       // [100,104)
            *(uint2*)&Hs[tid * SP + 204] = make_uint2(0, 0);       // [204,208)
            *(uint4*)&Hs[tid * SP + 216] = make_uint4(0, 0, 0, 0); // [216,224)
        }
        for (int i = tid; i < 224; i += 512)                        // pad rows 40..47
            *(uint4*)&Hs[(40 + i / 28) * SP + (i % 28) * 8] = make_uint4(0, 0, 0, 0);
        const unsigned short* x = (const unsigned short*)xin;
        for (int i = tid; i < 1000; i += 512) {                     // self [0,100)
            int r = i / 25, c = i % 25;
            *(uint2*)&Hs[r * SP + c * 4] = *(const uint2*)(x + (size_t)(R0 + r) * XS + c * 4);
        }
        for (int i = tid; i < 1000; i += 512) {                     // nbr [104,204)
            int r = i / 25, c = i % 25;
            *(uint2*)&Hs[r * SP + 104 + c * 4] = *(const uint2*)(Hg + (size_t)(R0 + r) * 100 + c * 4);
        }
        if (tid < 40)                                               // bond [208,216)
            *(uint4*)&Hs[tid * SP + 208] = *(const uint4*)(bsv2 + (size_t)(R0 + tid) * 8);
    } else {
        if (tid < 40) *(unsigned*)&Hs[tid * SP + 62] = 0;           // [62,64)
        for (int i = tid; i < 120; i += 512)                        // [136,160)
            *(uint4*)&Hs[(i / 3) * SP + 136 + (i % 3) * 8] = make_uint4(0, 0, 0, 0);
        for (int i = tid; i < 160; i += 512)                        // pad rows 40..47
            *(uint4*)&Hs[(40 + i / 20) * SP + (i % 20) * 8] = make_uint4(0, 0, 0, 0);
        const float* x = (const float*)xin;
        for (int i = tid; i < 1240; i += 512) {                     // self [0,62)
            int r = i / 31, c = i % 31;
            float2 v = *(const float2*)(x + (size_t)(R0 + r) * 62 + c * 2);
            *(unsigned*)&Hs[r * SP + c * 2] = pack2(v.x, v.y);
        }
        for (int i = tid; i < 320; i += 512) {                      // nbr [64,128)
            int r = i / 8, c = i % 8;
            *(uint4*)&Hs[r * SP + 64 + c * 8] = *(const uint4*)(Hg + (size_t)(R0 + r) * 64 + c * 8);
        }
        if (tid < 40)                                               // bond [128,136)
            *(uint4*)&Hs[tid * SP + 128] = *(const uint4*)(bsv2 + (size_t)(R0 + tid) * 8);
    }
    __syncthreads();

    // ---- MFMA GEMM: 3 M-tiles (48 rows) x NT N-tiles over 8 waves, K = KP
    const int lane = threadIdx.x & 63;
    const int wv   = threadIdx.x >> 6;     // 0..7
    const int n16  = lane & 15;
    const int quad = lane >> 4;

    float4v acc[JMAX][3];
    #pragma unroll
    for (int j = 0; j < JMAX; ++j)
        #pragma unroll
        for (int mt = 0; mt < 3; ++mt)
            acc[j][mt] = (float4v){0.f, 0.f, 0.f, 0.f};

    const unsigned short* Wb = Wt + (size_t)(deg - 1) * F_OUT_PAD * KP;

    for (int kk = 0; kk < KP; kk += 32) {
        short8 a[3];
        #pragma unroll
        for (int mt = 0; mt < 3; ++mt)
            a[mt] = *(const short8*)&Hs[(mt * 16 + n16) * SP + kk + quad * 8];
        short8 b[JMAX];
        #pragma unroll
        for (int j = 0; j < JMAX; ++j) {
            const int nt = wv + 8 * j;
            if (nt < NT)
                b[j] = *(const short8*)(Wb + (size_t)(nt * 16 + n16) * KP + kk + quad * 8);
        }
        #pragma unroll
        for (int j = 0; j < JMAX; ++j) {
            const int nt = wv + 8 * j;
            if (nt < NT)
                #pragma unroll
                for (int mt = 0; mt < 3; ++mt)
                    acc[j][mt] = __builtin_amdgcn_mfma_f32_16x16x32_bf16(
                        a[mt], b[j], acc[j][mt], 0, 0, 0);
        }
    }

    // ---- epilogue: bias, row ssq (quad shfl + cross-wave LDS), normalize
    // C/D layout: col = nt*16 + n16, row = mt*16 + quad*4 + r
    float ssq[3][4];
    #pragma unroll
    for (int mt = 0; mt < 3; ++mt)
        #pragma unroll
        for (int r = 0; r < 4; ++r) ssq[mt][r] = 0.f;

    #pragma unroll
    for (int j = 0; j < JMAX; ++j) {
        const int nt = wv + 8 * j;
        if (nt < NT) {
            const float bj = bcomb[(deg - 1) * F_OUT_PAD + nt * 16 + n16];
            #pragma unroll
            for (int mt = 0; mt < 3; ++mt)
                #pragma unroll
                for (int r = 0; r < 4; ++r) {
                    float t = acc[j][mt][r] + bj;
                    acc[j][mt][r] = t;
                    ssq[mt][r] += t * t;
                }
        }
    }
    #pragma unroll
    for (int off = 1; off <= 8; off <<= 1)
        #pragma unroll
        for (int mt = 0; mt < 3; ++mt)
            #pragma unroll
            for (int r = 0; r < 4; ++r)
                ssq[mt][r] += __shfl_xor(ssq[mt][r], off);
    if (n16 == 0)
        #pragma unroll
        for (int mt = 0; mt < 3; ++mt)
            #pragma unroll
            for (int r = 0; r < 4; ++r)
                ssqs[wv][mt * 16 + quad * 4 + r] = ssq[mt][r];
    __syncthreads();

    float rn[3][4];
    #pragma unroll
    for (int mt = 0; mt < 3; ++mt)
        #pragma unroll
        for (int r = 0; r < 4; ++r) {
            const int row = mt * 16 + quad * 4 + r;
            float s = 0.f;
            #pragma unroll
            for (int w = 0; w < 8; ++w) s += ssqs[w][row];
            rn[mt][r] = 1.0f / fmaxf(sqrtf(s), 1e-12f);
        }

    if constexpr (!LAST) {
        #pragma unroll
        for (int j = 0; j < JMAX; ++j) {
            const int nt = wv + 8 * j;
            if (nt < NT) {
                const int col = nt * 16 + n16;
                if (col < F_OUT) {
                    #pragma unroll
                    for (int mt = 0; mt < 3; ++mt)
                        #pragma unroll
                        for (int r = 0; r < 4; ++r) {
                            const int row = mt * 16 + quad * 4 + r;
                            if (row < 40) {
                                const float v = fmaxf(acc[j][mt][r] * rn[mt][r], 0.f);
                                xout[(size_t)(R0 + row) * XS + col] = f2bf(v);
                            }
                        }
                }
            }
        }
    } else {
        // fused molecule segment-sum: rows 0..19 -> mol 2*bid, 20..39 -> 2*bid+1
        #pragma unroll
        for (int j = 0; j < JMAX; ++j) {
            float m0 = 0.f, m1 = 0.f;
            #pragma unroll
            for (int mt = 0; mt < 3; ++mt)
                #pragma unroll
                for (int r = 0; r < 4; ++r) {
                    const int row = mt * 16 + quad * 4 + r;
                    if (row < 40) {
                        const float v = fmaxf(acc[j][mt][r] * rn[mt][r], 0.f);
                        if (row < 20) m0 += v; else m1 += v;
                    }
                }
            m0 += __shfl_xor(m0, 16); m0 += __shfl_xor(m0, 32);
            m1 += __shfl_xor(m1, 16); m1 += __shfl_xor(m1, 32);
            if (quad == 0) {
                const int col = (wv + 8 * j) * 16 + n16;
                molout[(size_t)(2 * blockIdx.x)     * 512 + col] = m0;
                molout[(size_t)(2 * blockIdx.x + 1) * 512 + col] = m1;
            }
        }
    }
}

// ======================= R6 fused fallback (proven; used if ws too small) ====
template<int DEG, int SP>
__device__ __forceinline__ void fgather_bf16(
    unsigned short* Hs, const unsigned short* __restrict__ x,
    const float* __restrict__ bondf,
    const int* __restrict__ an, const int* __restrict__ bn,
    int seg, int B40)
{
    const int tid = threadIdx.x;
    const int ch  = tid & 31;
    const int rg  = tid >> 5;
    if (ch < 25) {
        int ai[3][DEG];
        #pragma unroll
        for (int p = 0; p < 3; ++p) {
            const int r = rg + 16 * p;
            if (r < 40) {
                const int ri = B40 + r;
                #pragma unroll
                for (int d = 0; d < DEG; ++d) ai[p][d] = an[(size_t)ri * DEG + d];
            }
        }
        uint2 sv[3], nv[3][DEG];
        #pragma unroll
        for (int p = 0; p < 3; ++p) {
            const int r = rg + 16 * p;
            if (r < 40) {
                sv[p] = *(const uint2*)(x + (size_t)(seg + B40 + r) * XS + ch * 4);
                #pragma unroll
                for (int d = 0; d < DEG; ++d)
                    nv[p][d] = *(const uint2*)(x + (size_t)ai[p][d] * XS + ch * 4);
            }
        }
        #pragma unroll
        for (int p = 0; p < 3; ++p) {
            const int r = rg + 16 * p;
            if (r < 40) {
                unsigned short* hrow = Hs + r * SP;
                *(uint2*)(hrow + ch * 4) = sv[p];
                float s0 = 0.f, s1 = 0.f, s2 = 0.f, s3 = 0.f;
                #pragma unroll
                for (int d = 0; d < DEG; ++d) {
                    s0 += bf2f(nv[p][d].x & 0xFFFFu); s1 += bf2f(nv[p][d].x >> 16);
                    s2 += bf2f(nv[p][d].y & 0xFFFFu); s3 += bf2f(nv[p][d].y >> 16);
                }
                uint2 o; o.x = pack2(s0, s1); o.y = pack2(s2, s3);
                *(uint2*)(hrow + 104 + ch * 4) = o;
            }
        }
    } else {
        const int idx = rg * 7 + (ch - 25);
        if (idx < 40) {
            const int ri = B40 + idx;
            int bi[DEG];
            #pragma unroll
            for (int d = 0; d < DEG; ++d) bi[d] = bn[(size_t)ri * DEG + d];
            float2 v0[DEG], v1[DEG], v2[DEG];
            #pragma unroll
            for (int d = 0; d < DEG; ++d) {
                const float* bp = bondf + (size_t)bi[d] * 6;
                v0[d] = *(const float2*)bp;
                v1[d] = *(const float2*)(bp + 2);
                v2[d] = *(const float2*)(bp + 4);
            }
            float s0 = 0.f, s1 = 0.f, s2 = 0.f, s3 = 0.f, s4 = 0.f, s5 = 0.f;
            #pragma unroll
            for (int d = 0; d < DEG; ++d) {
                s0 += v0[d].x; s1 += v0[d].y; s2 += v1[d].x;
                s3 += v1[d].y; s4 += v2[d].x; s5 += v2[d].y;
            }
            unsigned short* hrow = Hs + idx * SP;
            uint4 w; w.x = pack2(s0, s1); w.y = pack2(s2, s3); w.z = pack2(s4, s5); w.w = 0;
            *(uint4*)(hrow + 208) = w;
            *(uint4*)(hrow + 216) = make_uint4(0, 0, 0, 0);
        }
    }
    for (int i = tid; i < 80; i += 512) {
        unsigned short* p = Hs + (i >> 1) * SP + ((i & 1) ? 204 : 100);
        *(uint2*)p = make_uint2(0, 0);
    }
    for (int i = tid; i < 8 * 28; i += 512)
        *(uint4*)(Hs + (40 + i / 28) * SP + (i % 28) * 8) = make_uint4(0, 0, 0, 0);
}

template<int DEG, int SP>
__device__ __forceinline__ void fgather_f32(
    unsigned short* Hs, const float* __restrict__ x,
    const float* __restrict__ bondf,
    const int* __restrict__ an, const int* __restrict__ bn,
    int seg, int B40)
{
    const int tid = threadIdx.x;
    const int ch  = tid & 31;
    const int rg  = tid >> 5;
    if (ch < 31) {
        int ai[3][DEG];
        #pragma unroll
        for (int p = 0; p < 3; ++p) {
            const int r = rg + 16 * p;
            if (r < 40) {
                const int ri = B40 + r;
                #pragma unroll
                for (int d = 0; d < DEG; ++d) ai[p][d] = an[(size_t)ri * DEG + d];
            }
        }
        float2 sv[3], nv[3][DEG];
        #pragma unroll
        for (int p = 0; p < 3; ++p) {
            const int r = rg + 16 * p;
            if (r < 40) {
                sv[p] = *(const float2*)(x + (size_t)(seg + B40 + r) * 62 + ch * 2);
                #pragma unroll
                for (int d = 0; d < DEG; ++d)
                    nv[p][d] = *(const float2*)(x + (size_t)ai[p][d] * 62 + ch * 2);
            }
        }
        #pragma unroll
        for (int p = 0; p < 3; ++p) {
            const int r = rg + 16 * p;
            if (r < 40) {
                unsigned short* hrow = Hs + r * SP;
                *(unsigned*)(hrow + ch * 2) = pack2(sv[p].x, sv[p].y);
                float s0 = 0.f, s1 = 0.f;
                #pragma unroll
                for (int d = 0; d < DEG; ++d) { s0 += nv[p][d].x; s1 += nv[p][d].y; }
                *(unsigned*)(hrow + 64 + ch * 2) = pack2(s0, s1);
            }
        }
    }
    if (tid < 40) {
        const int ri = B40 + tid;
        int bi[DEG];
        #pragma unroll
        for (int d = 0; d < DEG; ++d) bi[d] = bn[(size_t)ri * DEG + d];
        float2 v0[DEG], v1[DEG], v2[DEG];
        #pragma unroll
        for (int d = 0; d < DEG; ++d) {
            const float* bp = bondf + (size_t)bi[d] * 6;
            v0[d] = *(const float2*)bp;
            v1[d] = *(const float2*)(bp + 2);
            v2[d] = *(const float2*)(bp + 4);
        }
        float s0 = 0.f, s1 = 0.f, s2 = 0.f, s3 = 0.f, s4 = 0.f, s5 = 0.f;
        #pragma unroll
        for (int d = 0; d < DEG; ++d) {
            s0 += v0[d].x; s1 += v0[d].y; s2 += v1[d].x;
            s3 += v1[d].y; s4 += v2[d].x; s5 += v2[d].y;
        }
        unsigned short* hrow = Hs + tid * SP;
        uint4 w; w.x = pack2(s0, s1); w.y = pack2(s2, s3); w.z = pack2(s4, s5); w.w = 0;
        *(uint4*)(hrow + 128) = w;
        *(uint4*)(hrow + 136) = make_uint4(0, 0, 0, 0);
        *(uint4*)(hrow + 144) = make_uint4(0, 0, 0, 0);
        *(uint4*)(hrow + 152) = make_uint4(0, 0, 0, 0);
    }
    for (int i = tid; i < 80; i += 512)
        *(unsigned*)(Hs + (i >> 1) * SP + ((i & 1) ? 126 : 62)) = 0;
    for (int i = tid; i < 8 * 20; i += 512)
        *(uint4*)(Hs + (40 + i / 20) * SP + (i % 20) * 8) = make_uint4(0, 0, 0, 0);
}

template<int F_IN, int F_OUT, int F_OUT_PAD, int SELF_PAD, bool LAST, bool BF16IN>
__global__ __launch_bounds__(512, 4) void layer_fused(
    const void* __restrict__ xin,
    const float* __restrict__ bondf,
    const int* __restrict__ an1, const int* __restrict__ bn1,
    const int* __restrict__ an2, const int* __restrict__ bn2,
    const int* __restrict__ an3, const int* __restrict__ bn3,
    const int* __restrict__ an4, const int* __restrict__ bn4,
    const unsigned short* __restrict__ Wt,
    const float* __restrict__ bcomb,
    unsigned short* __restrict__ xout,
    float* __restrict__ molout)
{
    constexpr int KP   = (2 * SELF_PAD + 6 + 31) & ~31;
    constexpr int SP   = KP + 8;
    constexpr int NT   = F_OUT_PAD / 16;
    constexpr int JMAX = (NT + 7) / 8;

    __shared__ __align__(16) unsigned short Hs[48 * SP];
    __shared__ float ssqs[8][48];

    const int R0 = blockIdx.x * 40;
    int deg, seg; rowseg(R0, deg, seg);
    const int B40 = R0 - seg;

    if constexpr (BF16IN) {
        const unsigned short* x = (const unsigned short*)xin;
        switch (deg) {
            case 1: fgather_bf16<1, SP>(Hs, x, bondf, an1, bn1, seg, B40); break;
            case 2: fgather_bf16<2, SP>(Hs, x, bondf, an2, bn2, seg, B40); break;
            case 3: fgather_bf16<3, SP>(Hs, x, bondf, an3, bn3, seg, B40); break;
            default: fgather_bf16<4, SP>(Hs, x, bondf, an4, bn4, seg, B40); break;
        }
    } else {
        const float* x = (const float*)xin;
        switch (deg) {
            case 1: fgather_f32<1, SP>(Hs, x, bondf, an1, bn1, seg, B40); break;
            case 2: fgather_f32<2, SP>(Hs, x, bondf, an2, bn2, seg, B40); break;
            case 3: fgather_f32<3, SP>(Hs, x, bondf, an3, bn3, seg, B40); break;
            default: fgather_f32<4, SP>(Hs, x, bondf, an4, bn4, seg, B40); break;
        }
    }
    __syncthreads();

    const int lane = threadIdx.x & 63;
    const int wv   = threadIdx.x >> 6;
    const int n16  = lane & 15;
    const int quad = lane >> 4;

    float4v acc[JMAX][3];
    #pragma unroll
    for (int j = 0; j < JMAX; ++j)
        #pragma unroll
        for (int mt = 0; mt < 3; ++mt)
            acc[j][mt] = (float4v){0.f, 0.f, 0.f, 0.f};

    const unsigned short* Wb = Wt + (size_t)(deg - 1) * F_OUT_PAD * KP;

    for (int kk = 0; kk < KP; kk += 32) {
        short8 a[3];
        #pragma unroll
        for (int mt = 0; mt < 3; ++mt)
            a[mt] = *(const short8*)&Hs[(mt * 16 + n16) * SP + kk + quad * 8];
        short8 b[JMAX];
        #pragma unroll
        for (int j = 0; j < JMAX; ++j) {
            const int nt = wv + 8 * j;
            if (nt < NT)
                b[j] = *(const short8*)(Wb + (size_t)(nt * 16 + n16) * KP + kk + quad * 8);
        }
        #pragma unroll
        for (int j = 0; j < JMAX; ++j) {
            const int nt = wv + 8 * j;
            if (nt < NT)
                #pragma unroll
                for (int mt = 0; mt < 3; ++mt)
                    acc[j][mt] = __builtin_amdgcn_mfma_f32_16x16x32_bf16(
                        a[mt], b[j], acc[j][mt], 0, 0, 0);
        }
    }

    float ssq[3][4];
    #pragma unroll
    for (int mt = 0; mt < 3; ++mt)
        #pragma unroll
        for (int r = 0; r < 4; ++r) ssq[mt][r] = 0.f;
    #pragma unroll
    for (int j = 0; j < JMAX; ++j) {
        const int nt = wv + 8 * j;
        if (nt < NT) {
            const float bj = bcomb[(deg - 1) * F_OUT_PAD + nt * 16 + n16];
            #pragma unroll
            for (int mt = 0; mt < 3; ++mt)
                #pragma unroll
                for (int r = 0; r < 4; ++r) {
                    float t = acc[j][mt][r] + bj;
                    acc[j][mt][r] = t;
                    ssq[mt][r] += t * t;
                }
        }
    }
    #pragma unroll
    for (int off = 1; off <= 8; off <<= 1)
        #pragma unroll
        for (int mt = 0; mt < 3; ++mt)
            #pragma unroll
            for (int r = 0; r < 4; ++r)
                ssq[mt][r] += __shfl_xor(ssq[mt][r], off);
    if (n16 == 0)
        #pragma unroll
        for (int mt = 0; mt < 3; ++mt)
            #pragma unroll
            for (int r = 0; r < 4; ++r)
                ssqs[wv][mt * 16 + quad * 4 + r] = ssq[mt][r];
    __syncthreads();

    float rn[3][4];
    #pragma unroll
    for (int mt = 0; mt < 3; ++mt)
        #pragma unroll
        for (int r = 0; r < 4; ++r) {
            const int row = mt * 16 + quad * 4 + r;
            float s = 0.f;
            #pragma unroll
            for (int w = 0; w < 8; ++w) s += ssqs[w][row];
            rn[mt][r] = 1.0f / fmaxf(sqrtf(s), 1e-12f);
        }

    if constexpr (!LAST) {
        #pragma unroll
        for (int j = 0; j < JMAX; ++j) {
            const int nt = wv + 8 * j;
            if (nt < NT) {
                const int col = nt * 16 + n16;
                if (col < F_OUT) {
                    #pragma unroll
                    for (int mt = 0; mt < 3; ++mt)
                        #pragma unroll
                        for (int r = 0; r < 4; ++r) {
                            const int row = mt * 16 + quad * 4 + r;
                            if (row < 40) {
                                const float v = fmaxf(acc[j][mt][r] * rn[mt][r], 0.f);
                                xout[(size_t)(R0 + row) * XS + col] = f2bf(v);
                            }
                        }
                }
            }
        }
    } else {
        #pragma unroll
        for (int j = 0; j < JMAX; ++j) {
            float m0 = 0.f, m1 = 0.f;
            #pragma unroll
            for (int mt = 0; mt < 3; ++mt)
                #pragma unroll
                for (int r = 0; r < 4; ++r) {
                    const int row = mt * 16 + quad * 4 + r;
                    if (row < 40) {
                        const float v = fmaxf(acc[j][mt][r] * rn[mt][r], 0.f);
                        if (row < 20) m0 += v; else m1 += v;
                    }
                }
            m0 += __shfl_xor(m0, 16); m0 += __shfl_xor(m0, 32);
            m1 += __shfl_xor(m1, 16); m1 += __shfl_xor(m1, 32);
            if (quad == 0) {
                const int col = (wv + 8 * j) * 16 + n16;
                molout[(size_t)(2 * blockIdx.x)     * 512 + col] = m0;
                molout[(size_t)(2 * blockIdx.x + 1) * 512 + col] = m1;
            }
        }
    }
}

extern "C" void kernel_launch(void* const* d_in, const int* in_sizes, int n_in,
                              void* d_out, int out_size, void* d_ws, size_t ws_size,
                              hipStream_t stream) {
    const bool sig_order = (in_sizes[3] != 100000);

    const float* atomf = (const float*)d_in[0];   // [500000,62]
    const float* bondf = (const float*)d_in[1];   // [600000,6]
    const int *an1, *bn1, *an2, *bn2, *an3, *bn3, *an4, *bn4;
    const float *Ws0, *bs0, *Wd0, *bd0;
    const float *Ws1, *bs1, *Wd1, *bd1;
    const float *Ws2, *bs2, *Wd2, *bd2;

    if (!sig_order) {
        an1 = (const int*)d_in[2];  bn1 = (const int*)d_in[3];
        an2 = (const int*)d_in[4];  bn2 = (const int*)d_in[5];
        an3 = (const int*)d_in[6];  bn3 = (const int*)d_in[7];
        an4 = (const int*)d_in[8];  bn4 = (const int*)d_in[9];
        Ws0 = (const float*)d_in[11]; bs0 = (const float*)d_in[12];
        Wd0 = (const float*)d_in[13]; bd0 = (const float*)d_in[14];
        Ws1 = (const float*)d_in[15]; bs1 = (const float*)d_in[16];
        Wd1 = (const float*)d_in[17]; bd1 = (const float*)d_in[18];
        Ws2 = (const float*)d_in[19]; bs2 = (const float*)d_in[20];
        Wd2 = (const float*)d_in[21]; bd2 = (const float*)d_in[22];
    } else {
        an1 = (const int*)d_in[2];  an2 = (const int*)d_in[3];
        an3 = (const int*)d_in[4];  an4 = (const int*)d_in[5];
        bn1 = (const int*)d_in[6];  bn2 = (const int*)d_in[7];
        bn3 = (const int*)d_in[8];  bn4 = (const int*)d_in[9];
        Ws0 = (const float*)d_in[11]; bs0 = (const float*)d_in[12];
        Ws1 = (const float*)d_in[13]; bs1 = (const float*)d_in[14];
        Ws2 = (const float*)d_in[15]; bs2 = (const float*)d_in[16];
        Wd0 = (const float*)d_in[17]; bd0 = (const float*)d_in[18];
        Wd1 = (const float*)d_in[19]; bd1 = (const float*)d_in[20];
        Wd2 = (const float*)d_in[21]; bd2 = (const float*)d_in[22];
    }

    const size_t NEED_SPLIT = 309273344;   // X1+X2+HG+BS+weights
    char* w = (char*)d_ws;

    if (ws_size >= NEED_SPLIT) {
        // ---- split path layout
        unsigned short* x1  = (unsigned short*)w;                        // 100,000,000
        unsigned short* x2  = (unsigned short*)(w + 100000000);          // 100,000,000
        unsigned short* Hg  = (unsigned short*)(w + 200000000);          // 100,000,000
        unsigned short* BS  = (unsigned short*)(w + 300000000);          //   8,000,000
        unsigned short* Wt0 = (unsigned short*)(w + 308000000);          // 143,360
        float*          bc0 = (float*)(w + 308143360);                   // 1,792
        unsigned short* Wt1 = (unsigned short*)(w + 308145152);          // 200,704
        float*          bc1 = (float*)(w + 308345856);                   // 1,792
        unsigned short* Wt2 = (unsigned short*)(w + 308347648);          // 917,504
        float*          bc2 = (float*)(w + 309265152);                   // 8,192

        bond_prep<<<1954, 256, 0, stream>>>(bondf, bn1, bn2, bn3, bn4, BS);
        prep_weights<<<(4 * 112 * 160 + 255) / 256, 256, 0, stream>>>(
            Ws0, bs0, Wd0, bd0, 62, 100, 112, 160, 64, Wt0, bc0);
        prep_weights<<<(4 * 112 * 224 + 255) / 256, 256, 0, stream>>>(
            Ws1, bs1, Wd1, bd1, 100, 100, 112, 224, 104, Wt1, bc1);
        prep_weights<<<(4 * 512 * 224 + 255) / 256, 256, 0, stream>>>(
            Ws2, bs2, Wd2, bd2, 100, 512, 512, 224, 104, Wt2, bc2);

        gather_nbr_f32<<<31250, 256, 0, stream>>>(atomf, an1, an2, an3, an4, Hg);
        layer_gemm<62, 100, 112, 64, false, true><<<12500, 512, 0, stream>>>(
            atomf, Hg, BS, Wt0, bc0, x1, nullptr);
        gather_nbr_bf16<<<31250, 256, 0, stream>>>(x1, an1, an2, an3, an4, Hg);
        layer_gemm<100, 100, 112, 104, false, false><<<12500, 512, 0, stream>>>(
            x1, Hg, BS, Wt1, bc1, x2, nullptr);
        gather_nbr_bf16<<<31250, 256, 0, stream>>>(x2, an1, an2, an3, an4, Hg);
        layer_gemm<100, 512, 512, 104, true, false><<<12500, 512, 0, stream>>>(
            x2, Hg, BS, Wt2, bc2, nullptr, (float*)d_out);
    } else {
        // ---- R6 fused fallback (201,273,344 B proven)
        unsigned short* x1  = (unsigned short*)w;
        unsigned short* x2  = (unsigned short*)(w + 100000000);
        unsigned short* Wt0 = (unsigned short*)(w + 200000000);
        float*          bc0 = (float*)(w + 200143360);
        unsigned short* Wt1 = (unsigned short*)(w + 200145152);
        float*          bc1 = (float*)(w + 200345856);
        unsigned short* Wt2 = (unsigned short*)(w + 200347648);
        float*          bc2 = (float*)(w + 201265152);

        prep_weights<<<(4 * 112 * 160 + 255) / 256, 256, 0, stream>>>(
            Ws0, bs0, Wd0, bd0, 62, 100, 112, 160, 64, Wt0, bc0);
        prep_weights<<<(4 * 112 * 224 + 255) / 256, 256, 0, stream>>>(
            Ws1, bs1, Wd1, bd1, 100, 100, 112, 224, 104, Wt1, bc1);
        prep_weights<<<(4 * 512 * 224 + 255) / 256, 256, 0, stream>>>(
            Ws2, bs2, Wd2, bd2, 100, 512, 512, 224, 104, Wt2, bc2);

        dim3 grid(12500), block(512);
        layer_fused<62, 100, 112, 64, false, false><<<grid, block, 0, stream>>>(
            atomf, bondf, an1, bn1, an2, bn2, an3, bn3, an4, bn4,
            Wt0, bc0, x1, nullptr);
        layer_fused<100, 100, 112, 104, false, true><<<grid, block, 0, stream>>>(
            x1, bondf, an1, bn1, an2, bn2, an3, bn3, an4, bn4,
            Wt1, bc1, x2, nullptr);
        layer_fused<100, 512, 512, 104, true, true><<<grid, block, 0, stream>>>(
            x2, bondf, an1, bn1, an2, bn2, an3, bn3, an4, bn4,
            Wt2, bc2, nullptr, (float*)d_out);
    }
}

// Round 8
// 826.420 us; speedup vs baseline: 1.3805x; 1.3805x over previous
//
#include <hip/hip_runtime.h>

// NeuralConvNetwork (Duvenaud fingerprint GNN), MI355X.
// Round 8: fused structure (R7 split proved gather is NOT the serial cost:
// layer_gemm with zero scattered loads still ran 381us, VALUBusy 48%).
// Attack = epilogue VALU:
//   - rn finalize: 48 threads sum the wave partials, sqrt/rcp once per row,
//     broadcast via LDS rn48[]; all threads read back with b128 (was: every
//     thread redoing 96 adds + 12 sqrt + 12 rcp).
//   - layers 0/1 at 256 threads (R5 config, measured faster), layer 2 at 512.
//   - K-loop fully unrolled.

#define XS 100   // bf16 elems per intermediate activation row (exact)

typedef __attribute__((ext_vector_type(8))) short short8;
typedef __attribute__((ext_vector_type(4))) float float4v;

__device__ __forceinline__ float bf2f(unsigned u) { return __uint_as_float(u << 16); }
__device__ __forceinline__ unsigned short f2bf(float f) {
    unsigned b = __float_as_uint(f);
    return (unsigned short)((b + 0x7FFFu + ((b >> 16) & 1u)) >> 16);  // RNE
}
__device__ __forceinline__ unsigned pack2(float a, float b) {
    return (unsigned)f2bf(a) | ((unsigned)f2bf(b) << 16);
}
__device__ __forceinline__ void rowseg(int r, int& deg, int& seg) {
    if (r < 100000)      { deg = 1; seg = 0;      }
    else if (r < 275000) { deg = 2; seg = 100000; }
    else if (r < 425000) { deg = 3; seg = 275000; }
    else                 { deg = 4; seg = 425000; }
}

// ---- weight prep: Wt[dg][n][k]; k<F_IN -> Ws[k][n], SELF_PAD<=k<SELF_PAD+F_IN
//      -> Wd[dg][k-SELF_PAD][n], 2*SELF_PAD<=k<2*SELF_PAD+6 -> Wd bond rows.
__global__ void prep_weights(const float* __restrict__ Ws, const float* __restrict__ bs,
                             const float* __restrict__ Wd, const float* __restrict__ bd,
                             int F_IN, int F_OUT, int F_OUT_PAD, int KP, int SELF_PAD,
                             unsigned short* __restrict__ Wt, float* __restrict__ bc)
{
    int id = blockIdx.x * 256 + threadIdx.x;
    int total = 4 * F_OUT_PAD * KP;
    if (id >= total) return;
    int k  = id % KP;
    int nq = (id / KP) % F_OUT_PAD;
    int dg = id / (KP * F_OUT_PAD);
    float v = 0.f;
    if (nq < F_OUT) {
        if (k < F_IN)                                   v = Ws[(size_t)k * F_OUT + nq];
        else if (k >= SELF_PAD && k < SELF_PAD + F_IN)  v = Wd[((size_t)dg * (F_IN + 6) + (k - SELF_PAD)) * F_OUT + nq];
        else if (k >= 2 * SELF_PAD && k < 2 * SELF_PAD + 6)
            v = Wd[((size_t)dg * (F_IN + 6) + F_IN + (k - 2 * SELF_PAD)) * F_OUT + nq];
    }
    Wt[id] = f2bf(v);
    if (k == 0)
        bc[dg * F_OUT_PAD + nq] = (nq < F_OUT) ? (bs[nq] + bd[(size_t)dg * F_OUT + nq]) : 0.f;
}

// ======================= gathers, 256-thread variant (R5, proven) ============
template<int DEG, int SP>
__device__ __forceinline__ void g256_bf16(
    unsigned short* Hs, const unsigned short* __restrict__ x,
    const float* __restrict__ bondf,
    const int* __restrict__ an, const int* __restrict__ bn,
    int seg, int B40)
{
    const int tid = threadIdx.x;
    const int ch  = tid & 31;
    const int rr  = tid >> 5;                       // 0..7
    if (ch < 25) {
        int ai[5][DEG];
        #pragma unroll
        for (int p = 0; p < 5; ++p) {
            const int ri = B40 + rr + 8 * p;
            #pragma unroll
            for (int d = 0; d < DEG; ++d) ai[p][d] = an[(size_t)ri * DEG + d];
        }
        uint2 sv[5], nv[5][DEG];
        #pragma unroll
        for (int p = 0; p < 5; ++p) {
            const int atom = seg + B40 + rr + 8 * p;
            sv[p] = *(const uint2*)(x + (size_t)atom * XS + ch * 4);
            #pragma unroll
            for (int d = 0; d < DEG; ++d)
                nv[p][d] = *(const uint2*)(x + (size_t)ai[p][d] * XS + ch * 4);
        }
        #pragma unroll
        for (int p = 0; p < 5; ++p) {
            unsigned short* hrow = Hs + (rr + 8 * p) * SP;
            *(uint2*)(hrow + ch * 4) = sv[p];       // self: bit copy
            float s0 = 0.f, s1 = 0.f, s2 = 0.f, s3 = 0.f;
            #pragma unroll
            for (int d = 0; d < DEG; ++d) {
                s0 += bf2f(nv[p][d].x & 0xFFFFu); s1 += bf2f(nv[p][d].x >> 16);
                s2 += bf2f(nv[p][d].y & 0xFFFFu); s3 += bf2f(nv[p][d].y >> 16);
            }
            uint2 o; o.x = pack2(s0, s1); o.y = pack2(s2, s3);
            *(uint2*)(hrow + 104 + ch * 4) = o;
        }
    }
    if (tid < 40) {                                 // bond: one row per thread
        const int ri = B40 + tid;
        int bi[DEG];
        #pragma unroll
        for (int d = 0; d < DEG; ++d) bi[d] = bn[(size_t)ri * DEG + d];
        float2 v0[DEG], v1[DEG], v2[DEG];
        #pragma unroll
        for (int d = 0; d < DEG; ++d) {
            const float* bp = bondf + (size_t)bi[d] * 6;
            v0[d] = *(const float2*)bp;
            v1[d] = *(const float2*)(bp + 2);
            v2[d] = *(const float2*)(bp + 4);
        }
        float s0 = 0.f, s1 = 0.f, s2 = 0.f, s3 = 0.f, s4 = 0.f, s5 = 0.f;
        #pragma unroll
        for (int d = 0; d < DEG; ++d) {
            s0 += v0[d].x; s1 += v0[d].y; s2 += v1[d].x;
            s3 += v1[d].y; s4 += v2[d].x; s5 += v2[d].y;
        }
        unsigned short* hrow = Hs + tid * SP;
        uint4 w; w.x = pack2(s0, s1); w.y = pack2(s2, s3); w.z = pack2(s4, s5); w.w = 0;
        *(uint4*)(hrow + 208) = w;
        *(uint4*)(hrow + 216) = make_uint4(0, 0, 0, 0);
    }
    for (int i = tid; i < 80; i += 256) {
        unsigned short* p = Hs + (i >> 1) * SP + ((i & 1) ? 204 : 100);
        *(uint2*)p = make_uint2(0, 0);
    }
    for (int i = tid; i < 8 * 28; i += 256)
        *(uint4*)(Hs + (40 + i / 28) * SP + (i % 28) * 8) = make_uint4(0, 0, 0, 0);
}

template<int DEG, int SP>
__device__ __forceinline__ void g256_f32(
    unsigned short* Hs, const float* __restrict__ x,
    const float* __restrict__ bondf,
    const int* __restrict__ an, const int* __restrict__ bn,
    int seg, int B40)
{
    const int tid = threadIdx.x;
    const int ch  = tid & 31;
    const int rr  = tid >> 5;
    if (ch < 31) {
        int ai[5][DEG];
        #pragma unroll
        for (int p = 0; p < 5; ++p) {
            const int ri = B40 + rr + 8 * p;
            #pragma unroll
            for (int d = 0; d < DEG; ++d) ai[p][d] = an[(size_t)ri * DEG + d];
        }
        float2 sv[5], nv[5][DEG];
        #pragma unroll
        for (int p = 0; p < 5; ++p) {
            const int atom = seg + B40 + rr + 8 * p;
            sv[p] = *(const float2*)(x + (size_t)atom * 62 + ch * 2);
            #pragma unroll
            for (int d = 0; d < DEG; ++d)
                nv[p][d] = *(const float2*)(x + (size_t)ai[p][d] * 62 + ch * 2);
        }
        #pragma unroll
        for (int p = 0; p < 5; ++p) {
            unsigned short* hrow = Hs + (rr + 8 * p) * SP;
            *(unsigned*)(hrow + ch * 2) = pack2(sv[p].x, sv[p].y);
            float s0 = 0.f, s1 = 0.f;
            #pragma unroll
            for (int d = 0; d < DEG; ++d) { s0 += nv[p][d].x; s1 += nv[p][d].y; }
            *(unsigned*)(hrow + 64 + ch * 2) = pack2(s0, s1);
        }
    }
    if (tid < 40) {
        const int ri = B40 + tid;
        int bi[DEG];
        #pragma unroll
        for (int d = 0; d < DEG; ++d) bi[d] = bn[(size_t)ri * DEG + d];
        float2 v0[DEG], v1[DEG], v2[DEG];
        #pragma unroll
        for (int d = 0; d < DEG; ++d) {
            const float* bp = bondf + (size_t)bi[d] * 6;
            v0[d] = *(const float2*)bp;
            v1[d] = *(const float2*)(bp + 2);
            v2[d] = *(const float2*)(bp + 4);
        }
        float s0 = 0.f, s1 = 0.f, s2 = 0.f, s3 = 0.f, s4 = 0.f, s5 = 0.f;
        #pragma unroll
        for (int d = 0; d < DEG; ++d) {
            s0 += v0[d].x; s1 += v0[d].y; s2 += v1[d].x;
            s3 += v1[d].y; s4 += v2[d].x; s5 += v2[d].y;
        }
        unsigned short* hrow = Hs + tid * SP;
        uint4 w; w.x = pack2(s0, s1); w.y = pack2(s2, s3); w.z = pack2(s4, s5); w.w = 0;
        *(uint4*)(hrow + 128) = w;
        *(uint4*)(hrow + 136) = make_uint4(0, 0, 0, 0);
        *(uint4*)(hrow + 144) = make_uint4(0, 0, 0, 0);
        *(uint4*)(hrow + 152) = make_uint4(0, 0, 0, 0);
    }
    for (int i = tid; i < 80; i += 256)
        *(unsigned*)(Hs + (i >> 1) * SP + ((i & 1) ? 126 : 62)) = 0;
    for (int i = tid; i < 8 * 20; i += 256)
        *(uint4*)(Hs + (40 + i / 20) * SP + (i % 20) * 8) = make_uint4(0, 0, 0, 0);
}

// ======================= gather, 512-thread variant (R6, proven) =============
template<int DEG, int SP>
__device__ __forceinline__ void g512_bf16(
    unsigned short* Hs, const unsigned short* __restrict__ x,
    const float* __restrict__ bondf,
    const int* __restrict__ an, const int* __restrict__ bn,
    int seg, int B40)
{
    const int tid = threadIdx.x;
    const int ch  = tid & 31;
    const int rg  = tid >> 5;                       // 0..15
    if (ch < 25) {
        int ai[3][DEG];
        #pragma unroll
        for (int p = 0; p < 3; ++p) {
            const int r = rg + 16 * p;
            if (r < 40) {
                const int ri = B40 + r;
                #pragma unroll
                for (int d = 0; d < DEG; ++d) ai[p][d] = an[(size_t)ri * DEG + d];
            }
        }
        uint2 sv[3], nv[3][DEG];
        #pragma unroll
        for (int p = 0; p < 3; ++p) {
            const int r = rg + 16 * p;
            if (r < 40) {
                sv[p] = *(const uint2*)(x + (size_t)(seg + B40 + r) * XS + ch * 4);
                #pragma unroll
                for (int d = 0; d < DEG; ++d)
                    nv[p][d] = *(const uint2*)(x + (size_t)ai[p][d] * XS + ch * 4);
            }
        }
        #pragma unroll
        for (int p = 0; p < 3; ++p) {
            const int r = rg + 16 * p;
            if (r < 40) {
                unsigned short* hrow = Hs + r * SP;
                *(uint2*)(hrow + ch * 4) = sv[p];
                float s0 = 0.f, s1 = 0.f, s2 = 0.f, s3 = 0.f;
                #pragma unroll
                for (int d = 0; d < DEG; ++d) {
                    s0 += bf2f(nv[p][d].x & 0xFFFFu); s1 += bf2f(nv[p][d].x >> 16);
                    s2 += bf2f(nv[p][d].y & 0xFFFFu); s3 += bf2f(nv[p][d].y >> 16);
                }
                uint2 o; o.x = pack2(s0, s1); o.y = pack2(s2, s3);
                *(uint2*)(hrow + 104 + ch * 4) = o;
            }
        }
    } else {                                        // bond rows on ch 25..31
        const int idx = rg * 7 + (ch - 25);
        if (idx < 40) {
            const int ri = B40 + idx;
            int bi[DEG];
            #pragma unroll
            for (int d = 0; d < DEG; ++d) bi[d] = bn[(size_t)ri * DEG + d];
            float2 v0[DEG], v1[DEG], v2[DEG];
            #pragma unroll
            for (int d = 0; d < DEG; ++d) {
                const float* bp = bondf + (size_t)bi[d] * 6;
                v0[d] = *(const float2*)bp;
                v1[d] = *(const float2*)(bp + 2);
                v2[d] = *(const float2*)(bp + 4);
            }
            float s0 = 0.f, s1 = 0.f, s2 = 0.f, s3 = 0.f, s4 = 0.f, s5 = 0.f;
            #pragma unroll
            for (int d = 0; d < DEG; ++d) {
                s0 += v0[d].x; s1 += v0[d].y; s2 += v1[d].x;
                s3 += v1[d].y; s4 += v2[d].x; s5 += v2[d].y;
            }
            unsigned short* hrow = Hs + idx * SP;
            uint4 w; w.x = pack2(s0, s1); w.y = pack2(s2, s3); w.z = pack2(s4, s5); w.w = 0;
            *(uint4*)(hrow + 208) = w;
            *(uint4*)(hrow + 216) = make_uint4(0, 0, 0, 0);
        }
    }
    for (int i = tid; i < 80; i += 512) {
        unsigned short* p = Hs + (i >> 1) * SP + ((i & 1) ? 204 : 100);
        *(uint2*)p = make_uint2(0, 0);
    }
    for (int i = tid; i < 8 * 28; i += 512)
        *(uint4*)(Hs + (40 + i / 28) * SP + (i % 28) * 8) = make_uint4(0, 0, 0, 0);
}

// ======================= fused layer kernel ==================================
template<int F_IN, int F_OUT, int F_OUT_PAD, int SELF_PAD, bool LAST, bool BF16IN, int BLK>
__global__ __launch_bounds__(BLK, BLK == 512 ? 4 : 2) void layer_fused(
    const void* __restrict__ xin,
    const float* __restrict__ bondf,
    const int* __restrict__ an1, const int* __restrict__ bn1,
    const int* __restrict__ an2, const int* __restrict__ bn2,
    const int* __restrict__ an3, const int* __restrict__ bn3,
    const int* __restrict__ an4, const int* __restrict__ bn4,
    const unsigned short* __restrict__ Wt,  // [4][F_OUT_PAD][KP] bf16
    const float* __restrict__ bcomb,        // [4][F_OUT_PAD] fp32
    unsigned short* __restrict__ xout,      // layers 0/1: [500000, XS] bf16
    float* __restrict__ molout)             // layer 2:    [25000, 512] fp32
{
    constexpr int KP   = (2 * SELF_PAD + 6 + 31) & ~31;   // 160 / 224
    constexpr int SP   = KP + 8;
    constexpr int NT   = F_OUT_PAD / 16;                  // 7 / 32
    constexpr int NW   = BLK / 64;                        // 4 / 8
    constexpr int JMAX = (NT + NW - 1) / NW;              // 2 / 4

    __shared__ __align__(16) unsigned short Hs[48 * SP];
    __shared__ float ssqs[NW][48];
    __shared__ __align__(16) float rn48[48];

    const int R0 = blockIdx.x * 40;
    int deg, seg; rowseg(R0, deg, seg);
    const int B40 = R0 - seg;

    if constexpr (BF16IN) {
        const unsigned short* x = (const unsigned short*)xin;
        if constexpr (BLK == 256) {
            switch (deg) {
                case 1: g256_bf16<1, SP>(Hs, x, bondf, an1, bn1, seg, B40); break;
                case 2: g256_bf16<2, SP>(Hs, x, bondf, an2, bn2, seg, B40); break;
                case 3: g256_bf16<3, SP>(Hs, x, bondf, an3, bn3, seg, B40); break;
                default: g256_bf16<4, SP>(Hs, x, bondf, an4, bn4, seg, B40); break;
            }
        } else {
            switch (deg) {
                case 1: g512_bf16<1, SP>(Hs, x, bondf, an1, bn1, seg, B40); break;
                case 2: g512_bf16<2, SP>(Hs, x, bondf, an2, bn2, seg, B40); break;
                case 3: g512_bf16<3, SP>(Hs, x, bondf, an3, bn3, seg, B40); break;
                default: g512_bf16<4, SP>(Hs, x, bondf, an4, bn4, seg, B40); break;
            }
        }
    } else {
        const float* x = (const float*)xin;
        switch (deg) {
            case 1: g256_f32<1, SP>(Hs, x, bondf, an1, bn1, seg, B40); break;
            case 2: g256_f32<2, SP>(Hs, x, bondf, an2, bn2, seg, B40); break;
            case 3: g256_f32<3, SP>(Hs, x, bondf, an3, bn3, seg, B40); break;
            default: g256_f32<4, SP>(Hs, x, bondf, an4, bn4, seg, B40); break;
        }
    }
    __syncthreads();

    // ---- MFMA GEMM: 3 M-tiles (48 rows) x NT N-tiles over NW waves, K = KP
    const int lane = threadIdx.x & 63;
    const int wv   = threadIdx.x >> 6;
    const int n16  = lane & 15;
    const int quad = lane >> 4;

    float4v acc[JMAX][3];
    #pragma unroll
    for (int j = 0; j < JMAX; ++j)
        #pragma unroll
        for (int mt = 0; mt < 3; ++mt)
            acc[j][mt] = (float4v){0.f, 0.f, 0.f, 0.f};

    const unsigned short* Wb = Wt + (size_t)(deg - 1) * F_OUT_PAD * KP;

    #pragma unroll
    for (int kk = 0; kk < KP; kk += 32) {
        short8 a[3];
        #pragma unroll
        for (int mt = 0; mt < 3; ++mt)
            a[mt] = *(const short8*)&Hs[(mt * 16 + n16) * SP + kk + quad * 8];
        short8 b[JMAX];
        #pragma unroll
        for (int j = 0; j < JMAX; ++j) {
            const int nt = wv + NW * j;
            if (nt < NT)
                b[j] = *(const short8*)(Wb + (size_t)(nt * 16 + n16) * KP + kk + quad * 8);
        }
        #pragma unroll
        for (int j = 0; j < JMAX; ++j) {
            const int nt = wv + NW * j;
            if (nt < NT)
                #pragma unroll
                for (int mt = 0; mt < 3; ++mt)
                    acc[j][mt] = __builtin_amdgcn_mfma_f32_16x16x32_bf16(
                        a[mt], b[j], acc[j][mt], 0, 0, 0);
        }
    }

    // ---- epilogue. C/D layout: col = nt*16 + n16, row = mt*16 + quad*4 + r
    float ssq[3][4];
    #pragma unroll
    for (int mt = 0; mt < 3; ++mt)
        #pragma unroll
        for (int r = 0; r < 4; ++r) ssq[mt][r] = 0.f;

    #pragma unroll
    for (int j = 0; j < JMAX; ++j) {
        const int nt = wv + NW * j;
        if (nt < NT) {
            const float bj = bcomb[(deg - 1) * F_OUT_PAD + nt * 16 + n16];
            #pragma unroll
            for (int mt = 0; mt < 3; ++mt)
                #pragma unroll
                for (int r = 0; r < 4; ++r) {
                    float t = acc[j][mt][r] + bj;
                    acc[j][mt][r] = t;
                    ssq[mt][r] += t * t;
                }
        }
    }
    #pragma unroll
    for (int off = 1; off <= 8; off <<= 1)
        #pragma unroll
        for (int mt = 0; mt < 3; ++mt)
            #pragma unroll
            for (int r = 0; r < 4; ++r)
                ssq[mt][r] += __shfl_xor(ssq[mt][r], off);
    if (n16 == 0)
        #pragma unroll
        for (int mt = 0; mt < 3; ++mt)
            #pragma unroll
            for (int r = 0; r < 4; ++r)
                ssqs[wv][mt * 16 + quad * 4 + r] = ssq[mt][r];
    __syncthreads();

    // single finalize pass: one sqrt/rcp per row, broadcast via rn48
    if (threadIdx.x < 48) {
        float s = 0.f;
        #pragma unroll
        for (int w = 0; w < NW; ++w) s += ssqs[w][threadIdx.x];
        rn48[threadIdx.x] = 1.0f / fmaxf(sqrtf(s), 1e-12f);
    }
    __syncthreads();

    float rn[3][4];
    #pragma unroll
    for (int mt = 0; mt < 3; ++mt) {
        float4 v = *(const float4*)&rn48[mt * 16 + quad * 4];
        rn[mt][0] = v.x; rn[mt][1] = v.y; rn[mt][2] = v.z; rn[mt][3] = v.w;
    }

    if constexpr (!LAST) {
        #pragma unroll
        for (int j = 0; j < JMAX; ++j) {
            const int nt = wv + NW * j;
            if (nt < NT) {
                const int col = nt * 16 + n16;
                if (col < F_OUT) {
                    #pragma unroll
                    for (int mt = 0; mt < 3; ++mt)
                        #pragma unroll
                        for (int r = 0; r < 4; ++r) {
                            const int row = mt * 16 + quad * 4 + r;
                            if (row < 40) {
                                const float v = fmaxf(acc[j][mt][r] * rn[mt][r], 0.f);
                                xout[(size_t)(R0 + row) * XS + col] = f2bf(v);
                            }
                        }
                }
            }
        }
    } else {
        // fused molecule segment-sum: rows 0..19 -> mol 2*bid, 20..39 -> 2*bid+1
        #pragma unroll
        for (int j = 0; j < JMAX; ++j) {
            float m0 = 0.f, m1 = 0.f;
            #pragma unroll
            for (int mt = 0; mt < 3; ++mt)
                #pragma unroll
                for (int r = 0; r < 4; ++r) {
                    const int row = mt * 16 + quad * 4 + r;
                    if (row < 40) {
                        const float v = fmaxf(acc[j][mt][r] * rn[mt][r], 0.f);
                        if (row < 20) m0 += v; else m1 += v;
                    }
                }
            m0 += __shfl_xor(m0, 16); m0 += __shfl_xor(m0, 32);
            m1 += __shfl_xor(m1, 16); m1 += __shfl_xor(m1, 32);
            if (quad == 0) {
                const int col = (wv + NW * j) * 16 + n16;
                molout[(size_t)(2 * blockIdx.x)     * 512 + col] = m0;
                molout[(size_t)(2 * blockIdx.x + 1) * 512 + col] = m1;
            }
        }
    }
}

extern "C" void kernel_launch(void* const* d_in, const int* in_sizes, int n_in,
                              void* d_out, int out_size, void* d_ws, size_t ws_size,
                              hipStream_t stream) {
    const bool sig_order = (in_sizes[3] != 100000);

    const float* atomf = (const float*)d_in[0];   // [500000,62]
    const float* bondf = (const float*)d_in[1];   // [600000,6]
    const int *an1, *bn1, *an2, *bn2, *an3, *bn3, *an4, *bn4;
    const float *Ws0, *bs0, *Wd0, *bd0;
    const float *Ws1, *bs1, *Wd1, *bd1;
    const float *Ws2, *bs2, *Wd2, *bd2;

    if (!sig_order) {
        an1 = (const int*)d_in[2];  bn1 = (const int*)d_in[3];
        an2 = (const int*)d_in[4];  bn2 = (const int*)d_in[5];
        an3 = (const int*)d_in[6];  bn3 = (const int*)d_in[7];
        an4 = (const int*)d_in[8];  bn4 = (const int*)d_in[9];
        Ws0 = (const float*)d_in[11]; bs0 = (const float*)d_in[12];
        Wd0 = (const float*)d_in[13]; bd0 = (const float*)d_in[14];
        Ws1 = (const float*)d_in[15]; bs1 = (const float*)d_in[16];
        Wd1 = (const float*)d_in[17]; bd1 = (const float*)d_in[18];
        Ws2 = (const float*)d_in[19]; bs2 = (const float*)d_in[20];
        Wd2 = (const float*)d_in[21]; bd2 = (const float*)d_in[22];
    } else {
        an1 = (const int*)d_in[2];  an2 = (const int*)d_in[3];
        an3 = (const int*)d_in[4];  an4 = (const int*)d_in[5];
        bn1 = (const int*)d_in[6];  bn2 = (const int*)d_in[7];
        bn3 = (const int*)d_in[8];  bn4 = (const int*)d_in[9];
        Ws0 = (const float*)d_in[11]; bs0 = (const float*)d_in[12];
        Ws1 = (const float*)d_in[13]; bs1 = (const float*)d_in[14];
        Ws2 = (const float*)d_in[15]; bs2 = (const float*)d_in[16];
        Wd0 = (const float*)d_in[17]; bd0 = (const float*)d_in[18];
        Wd1 = (const float*)d_in[19]; bd1 = (const float*)d_in[20];
        Wd2 = (const float*)d_in[21]; bd2 = (const float*)d_in[22];
    }

    // workspace layout (201,273,344 B — proven footprint)
    char* w = (char*)d_ws;
    unsigned short* x1  = (unsigned short*)w;                        // 100,000,000 B
    unsigned short* x2  = (unsigned short*)(w + 100000000);          // 100,000,000 B
    unsigned short* Wt0 = (unsigned short*)(w + 200000000);          // 143,360
    float*          bc0 = (float*)(w + 200143360);                   // 1,792
    unsigned short* Wt1 = (unsigned short*)(w + 200145152);          // 200,704
    float*          bc1 = (float*)(w + 200345856);                   // 1,792
    unsigned short* Wt2 = (unsigned short*)(w + 200347648);          // 917,504
    float*          bc2 = (float*)(w + 201265152);                   // 8,192

    prep_weights<<<(4 * 112 * 160 + 255) / 256, 256, 0, stream>>>(
        Ws0, bs0, Wd0, bd0, 62, 100, 112, 160, 64, Wt0, bc0);
    prep_weights<<<(4 * 112 * 224 + 255) / 256, 256, 0, stream>>>(
        Ws1, bs1, Wd1, bd1, 100, 100, 112, 224, 104, Wt1, bc1);
    prep_weights<<<(4 * 512 * 224 + 255) / 256, 256, 0, stream>>>(
        Ws2, bs2, Wd2, bd2, 100, 512, 512, 224, 104, Wt2, bc2);

    layer_fused<62, 100, 112, 64, false, false, 256><<<12500, 256, 0, stream>>>(
        atomf, bondf, an1, bn1, an2, bn2, an3, bn3, an4, bn4,
        Wt0, bc0, x1, nullptr);
    layer_fused<100, 100, 112, 104, false, true, 256><<<12500, 256, 0, stream>>>(
        x1, bondf, an1, bn1, an2, bn2, an3, bn3, an4, bn4,
        Wt1, bc1, x2, nullptr);
    layer_fused<100, 512, 512, 104, true, true, 512><<<12500, 512, 0, stream>>>(
        x2, bondf, an1, bn1, an2, bn2, an3, bn3, an4, bn4,
        Wt2, bc2, nullptr, (float*)d_out);
}